// Round 6
// baseline (87.999 us; speedup 1.0000x reference)
//
#include <hip/hip_runtime.h>

// LatencyEncoder R5: make the store loop instruction-identical to a blit.
// R4 post-mortem: nt-stores neutral -> write-allocate not the limiter; VALU &
// occupancy arithmetic clear R0's select-stream with margin, yet we sustain
// 8.0 B/cyc/CU vs the harness fill's 11.1. Hypothesis: per-store dependency
// baggage (ds_read+lgkmcnt gate, magic-div, 8 cndmask, bounds guard per store)
// creates issue-stream gaps. Test: materialize one-hot rows in LDS, then copy
// out with a pure ds_read_b128 -> global_store_dwordx4 loop (zero VALU).
//
//  - 128 pairs/block, 256 threads, LDS = 128*100*4 = 51,200 B -> 3 blocks/CU.
//  - Phase 1a: zero LDS (13 ds_write_b128 / thread, linear).
//  - barrier (cross-wave zero/scatter race).
//  - Phase 1b: threads 0..127 compute latency in f64 (chain matches numpy ref
//    bit-exactly; absmax 0.0 in R0/R1/R2/R4) and ds_write 1.0f at [tid][lat].
//  - barrier.
//  - Phase 2: pure copy, 12.5 float4/thread, exact-fit fast path (no guards).

#define T 100
#define PPB 128                    // pairs per block
#define LDSF4 (PPB * T / 4)        // 3200 float4s = 51,200 B

typedef float vf4 __attribute__((ext_vector_type(4)));

__global__ __launch_bounds__(256) void latency_encode_kernel(
    const float* __restrict__ x, const float* __restrict__ noise,
    float* __restrict__ out, int npairs) {
  __shared__ vf4 row[LDSF4];

  const int tid = threadIdx.x;
  const long long base = (long long)blockIdx.x * PPB;

  // ---- Phase 1a: zero the LDS tile (linear, conflict-free) ----
  const vf4 z = 0.0f;
#pragma unroll
  for (int k = 0; k < 13; ++k) {
    const int i = tid + k * 256;
    if (i < LDSF4) row[i] = z;
  }
  __syncthreads();  // zeroing crosses waves; spike scatter must come after

  // ---- Phase 1b: latency in f64 (matches numpy ref), scatter spike ----
  if (tid < PPB) {
    const long long p = base + tid;
    if (p < npairs) {
      double xn = (double)x[p] + (double)noise[p] * 0.01;
      double s = 1.0 / (1.0 + exp(-xn));
      if (s > 0.5) {
        int li = (int)rint((1.0 - s) * 99.0);
        li = li < 0 ? 0 : (li > 99 ? 99 : li);
        ((float*)row)[tid * T + li] = 1.0f;
      }
    }
  }
  __syncthreads();

  // ---- Phase 2: pure LDS -> global copy (no VALU in the stream) ----
  vf4* __restrict__ o4 = (vf4*)(out + base * T);
  if (base + PPB <= npairs) {
#pragma unroll
    for (int k = 0; k < 12; ++k) o4[tid + k * 256] = row[tid + k * 256];
    {
      const int i = tid + 12 * 256;          // 3072..3327, keep i < 3200
      if (i < LDSF4) o4[i] = row[i];
    }
  } else if (base < npairs) {
    const long long lim4 = ((long long)npairs - base) * T / 4;
    for (int i = tid; i < LDSF4; i += 256)
      if (i < lim4) o4[i] = row[i];
  }
}

extern "C" void kernel_launch(void* const* d_in, const int* in_sizes, int n_in,
                              void* d_out, int out_size, void* d_ws, size_t ws_size,
                              hipStream_t stream) {
  const float* x = (const float*)d_in[0];
  const float* noise = (const float*)d_in[1];
  float* out = (float*)d_out;
  const int npairs = in_sizes[0];  // 1,048,576
  const int grid = (npairs + PPB - 1) / PPB;  // 8192
  latency_encode_kernel<<<grid, 256, 0, stream>>>(x, noise, out, npairs);
}